// Round 1
// baseline (16718.918 us; speedup 1.0000x reference)
//
#include <hip/hip_runtime.h>

#define LNUM 6
#define EDIM 1024
#define HNUM 8
#define DHD  128
#define RNUM 33
#define FFD  4096
#define BNUM 8
#define SLEN 512
#define BSROWS (BNUM*SLEN)   // 4096

// ---------------- LayerNorm: one block per row of E=1024 ----------------
__global__ __launch_bounds__(256) void ln_kernel(const float* __restrict__ x,
                                                 const float* __restrict__ g,
                                                 const float* __restrict__ be,
                                                 float* __restrict__ o) {
  int row = blockIdx.x;
  int t = threadIdx.x;
  const float* xr = x + (size_t)row * EDIM;
  float4 xv = *reinterpret_cast<const float4*>(xr + t * 4);
  float s1 = xv.x + xv.y + xv.z + xv.w;
  float s2 = xv.x*xv.x + xv.y*xv.y + xv.z*xv.z + xv.w*xv.w;
#pragma unroll
  for (int off = 32; off >= 1; off >>= 1) {
    s1 += __shfl_down(s1, off, 64);
    s2 += __shfl_down(s2, off, 64);
  }
  __shared__ float r1[4], r2[4];
  if ((t & 63) == 0) { r1[t >> 6] = s1; r2[t >> 6] = s2; }
  __syncthreads();
  s1 = r1[0] + r1[1] + r1[2] + r1[3];
  s2 = r2[0] + r2[1] + r2[2] + r2[3];
  float mean = s1 * (1.0f / EDIM);
  float var  = s2 * (1.0f / EDIM) - mean * mean;
  float rstd = rsqrtf(var + 1e-5f);
  float4 gv = *reinterpret_cast<const float4*>(g + t * 4);
  float4 bv = *reinterpret_cast<const float4*>(be + t * 4);
  float4 ov;
  ov.x = (xv.x - mean) * rstd * gv.x + bv.x;
  ov.y = (xv.y - mean) * rstd * gv.y + bv.y;
  ov.z = (xv.z - mean) * rstd * gv.z + bv.z;
  ov.w = (xv.w - mean) * rstd * gv.w + bv.w;
  *reinterpret_cast<float4*>(o + (size_t)row * EDIM + t * 4) = ov;
}

// ---------------- Tiled f32 GEMM: C[M,N] = A[M,K] @ W[K,N] + bias ----------------
// FUSE: 0 = none, 1 = += res, 2 = relu
#define BM 128
#define BN 64
#define BKK 16

template<int FUSE>
__global__ __launch_bounds__(256) void gemm_f32(const float* __restrict__ A,
                                                const float* __restrict__ W,
                                                const float* __restrict__ bias,
                                                const float* __restrict__ res,
                                                float* __restrict__ C,
                                                int N, int K) {
  __shared__ float As[BKK][BM];   // A tile transposed: As[k][m]
  __shared__ float Bs[BKK][BN];
  int t  = threadIdx.x;
  int tx = t & 15;      // output col group (4 cols)
  int ty = t >> 4;      // output row group (8 rows)
  int m0 = blockIdx.y * BM;
  int n0 = blockIdx.x * BN;
  float acc[8][4] = {};
  int arow = t >> 1;           // 0..127
  int acol = (t & 1) * 8;      // 0 or 8
  int brow = t >> 4;           // 0..15
  int bcol = (t & 15) * 4;     // 0..60
  const float* Ap = A + (size_t)(m0 + arow) * K + acol;
  const float* Wp = W + (size_t)brow * N + n0 + bcol;
  for (int k0 = 0; k0 < K; k0 += BKK) {
    float4 a0 = *reinterpret_cast<const float4*>(Ap + k0);
    float4 a1 = *reinterpret_cast<const float4*>(Ap + k0 + 4);
    float4 b0 = *reinterpret_cast<const float4*>(Wp + (size_t)k0 * N);
    __syncthreads();   // previous iteration's LDS reads done
    As[acol + 0][arow] = a0.x; As[acol + 1][arow] = a0.y;
    As[acol + 2][arow] = a0.z; As[acol + 3][arow] = a0.w;
    As[acol + 4][arow] = a1.x; As[acol + 5][arow] = a1.y;
    As[acol + 6][arow] = a1.z; As[acol + 7][arow] = a1.w;
    *reinterpret_cast<float4*>(&Bs[brow][bcol]) = b0;
    __syncthreads();
#pragma unroll
    for (int kk = 0; kk < BKK; ++kk) {
      float4 av0 = *reinterpret_cast<const float4*>(&As[kk][ty * 8]);
      float4 av1 = *reinterpret_cast<const float4*>(&As[kk][ty * 8 + 4]);
      float4 bv  = *reinterpret_cast<const float4*>(&Bs[kk][tx * 4]);
      float a[8] = {av0.x, av0.y, av0.z, av0.w, av1.x, av1.y, av1.z, av1.w};
      float bb[4] = {bv.x, bv.y, bv.z, bv.w};
#pragma unroll
      for (int i2 = 0; i2 < 8; ++i2)
#pragma unroll
        for (int j2 = 0; j2 < 4; ++j2)
          acc[i2][j2] += a[i2] * bb[j2];
    }
  }
  int cx = n0 + tx * 4;
  float4 bias4 = *reinterpret_cast<const float4*>(bias + cx);
#pragma unroll
  for (int i2 = 0; i2 < 8; ++i2) {
    int rm = m0 + ty * 8 + i2;
    float o0 = acc[i2][0] + bias4.x;
    float o1 = acc[i2][1] + bias4.y;
    float o2 = acc[i2][2] + bias4.z;
    float o3 = acc[i2][3] + bias4.w;
    if (FUSE == 2) {
      o0 = fmaxf(o0, 0.f); o1 = fmaxf(o1, 0.f);
      o2 = fmaxf(o2, 0.f); o3 = fmaxf(o3, 0.f);
    }
    if (FUSE == 1) {
      float4 rv = *reinterpret_cast<const float4*>(res + (size_t)rm * N + cx);
      o0 += rv.x; o1 += rv.y; o2 += rv.z; o3 += rv.w;
    }
    *reinterpret_cast<float4*>(C + (size_t)rm * N + cx) = make_float4(o0, o1, o2, o3);
  }
}

// ---------------- Relational attention: one block per (b, h, i) ----------------
__global__ __launch_bounds__(256) void attn_kernel(const float* __restrict__ q,
                                                   const float* __restrict__ k,
                                                   const float* __restrict__ v,
                                                   const int* __restrict__ rel,
                                                   const int* __restrict__ lens,
                                                   const float* __restrict__ relk,
                                                   const float* __restrict__ relv,
                                                   float* __restrict__ out) {
  __shared__ float qs[DHD];
  __shared__ float kt[32][132];          // K/V tile, padded stride
  __shared__ float sc[SLEN];
  __shared__ float qr[RNUM];
  __shared__ float arel[RNUM];
  __shared__ float red[8];

  int t  = threadIdx.x;
  int bi = blockIdx.x;
  int i  = bi & (SLEN - 1);
  int bh = bi >> 9;
  int hh = bh & (HNUM - 1);
  int b  = bh >> 3;
  int len = lens[b];
  bool validi = (i < len);
  size_t rowq = ((size_t)(b * SLEN + i)) * EDIM + hh * DHD;

  if (t < 32)
    *reinterpret_cast<float4*>(&qs[t * 4]) =
        *reinterpret_cast<const float4*>(q + rowq + t * 4);
  if (t < RNUM) arel[t] = 0.f;
  __syncthreads();
  if (t < RNUM) {
    float s = 0.f;
    for (int d = 0; d < DHD; ++d) s += qs[d] * relk[t * DHD + d];
    qr[t] = s;
  }

  const int* relrow = rel + ((size_t)(b * SLEN + i)) * SLEN;
  const float scale = 0.08838834764831845f;   // 1/sqrt(128)

  // ---- scores ----
  for (int jt = 0; jt < SLEN; jt += 32) {
    __syncthreads();
    {
      int row  = t >> 3;
      int cseg = (t & 7) * 16;
      const float* kp = k + ((size_t)(b * SLEN + jt + row)) * EDIM + hh * DHD + cseg;
      float4 x0 = *reinterpret_cast<const float4*>(kp + 0);
      float4 x1 = *reinterpret_cast<const float4*>(kp + 4);
      float4 x2 = *reinterpret_cast<const float4*>(kp + 8);
      float4 x3 = *reinterpret_cast<const float4*>(kp + 12);
      *reinterpret_cast<float4*>(&kt[row][cseg + 0])  = x0;
      *reinterpret_cast<float4*>(&kt[row][cseg + 4])  = x1;
      *reinterpret_cast<float4*>(&kt[row][cseg + 8])  = x2;
      *reinterpret_cast<float4*>(&kt[row][cseg + 12]) = x3;
    }
    __syncthreads();
    int j = t >> 3;
    int part = t & 7;
    int dbase = part * 16;
    float p = 0.f;
#pragma unroll
    for (int dd = 0; dd < 16; dd += 4) {
      float4 kk4 = *reinterpret_cast<const float4*>(&kt[j][dbase + dd]);
      float4 qq4 = *reinterpret_cast<const float4*>(&qs[dbase + dd]);
      p += kk4.x * qq4.x + kk4.y * qq4.y + kk4.z * qq4.z + kk4.w * qq4.w;
    }
    p += __shfl_down(p, 4, 8);
    p += __shfl_down(p, 2, 8);
    p += __shfl_down(p, 1, 8);
    if (part == 0) {
      int jj = jt + j;
      int r = relrow[jj];
      float sv = (p + qr[r]) * scale;
      sc[jj] = (validi && jj < len) ? sv : -1e9f;
    }
  }
  __syncthreads();

  // ---- softmax over 512 ----
  float e0 = sc[t], e1 = sc[t + 256];
  float mx = fmaxf(e0, e1);
#pragma unroll
  for (int off = 32; off >= 1; off >>= 1) mx = fmaxf(mx, __shfl_down(mx, off, 64));
  if ((t & 63) == 0) red[t >> 6] = mx;
  __syncthreads();
  mx = fmaxf(fmaxf(red[0], red[1]), fmaxf(red[2], red[3]));
  e0 = __expf(e0 - mx);
  e1 = __expf(e1 - mx);
  float sm = e0 + e1;
#pragma unroll
  for (int off = 32; off >= 1; off >>= 1) sm += __shfl_down(sm, off, 64);
  if ((t & 63) == 0) red[4 + (t >> 6)] = sm;
  __syncthreads();
  sm = red[4] + red[5] + red[6] + red[7];
  float inv = 1.0f / sm;
  e0 *= inv; e1 *= inv;
  sc[t] = e0;
  sc[t + 256] = e1;
  atomicAdd(&arel[relrow[t]], e0);
  atomicAdd(&arel[relrow[t + 256]], e1);

  // ---- PV ----
  int d = t & 127;
  int half = t >> 7;
  float acc = 0.f;
  for (int jt = 0; jt < SLEN; jt += 32) {
    __syncthreads();
    {
      int row  = t >> 3;
      int cseg = (t & 7) * 16;
      const float* vp = v + ((size_t)(b * SLEN + jt + row)) * EDIM + hh * DHD + cseg;
      float4 x0 = *reinterpret_cast<const float4*>(vp + 0);
      float4 x1 = *reinterpret_cast<const float4*>(vp + 4);
      float4 x2 = *reinterpret_cast<const float4*>(vp + 8);
      float4 x3 = *reinterpret_cast<const float4*>(vp + 12);
      *reinterpret_cast<float4*>(&kt[row][cseg + 0])  = x0;
      *reinterpret_cast<float4*>(&kt[row][cseg + 4])  = x1;
      *reinterpret_cast<float4*>(&kt[row][cseg + 8])  = x2;
      *reinterpret_cast<float4*>(&kt[row][cseg + 12]) = x3;
    }
    __syncthreads();
    int j0 = half * 16;
#pragma unroll
    for (int jj = 0; jj < 16; ++jj)
      acc += sc[jt + j0 + jj] * kt[j0 + jj][d];
  }
  __syncthreads();
  float* comb = reinterpret_cast<float*>(kt);
  if (half) comb[d] = acc;
  __syncthreads();
  if (!half) {
    acc += comb[d];
    float biasv = 0.f;
    for (int r = 0; r < RNUM; ++r) biasv += arel[r] * relv[r * DHD + d];
    out[rowq + d] = acc + biasv;
  }
}

// ---------------- host ----------------
extern "C" void kernel_launch(void* const* d_in, const int* in_sizes, int n_in,
                              void* d_out, int out_size, void* d_ws, size_t ws_size,
                              hipStream_t stream) {
  const float* enc  = (const float*)d_in[0];
  const int*   rel  = (const int*)d_in[1];
  const int*   lens = (const int*)d_in[2];
  const float* Wq = (const float*)d_in[3];
  const float* bq = (const float*)d_in[4];
  const float* Wk = (const float*)d_in[5];
  const float* bk = (const float*)d_in[6];
  const float* Wv = (const float*)d_in[7];
  const float* bv = (const float*)d_in[8];
  const float* Wo = (const float*)d_in[9];
  const float* bo = (const float*)d_in[10];
  const float* relk = (const float*)d_in[11];
  const float* relv = (const float*)d_in[12];
  const float* W1 = (const float*)d_in[13];
  const float* b1 = (const float*)d_in[14];
  const float* W2 = (const float*)d_in[15];
  const float* b2 = (const float*)d_in[16];
  const float* ln1g = (const float*)d_in[17];
  const float* ln1b = (const float*)d_in[18];
  const float* ln2g = (const float*)d_in[19];
  const float* ln2b = (const float*)d_in[20];
  const float* lnfg = (const float*)d_in[21];
  const float* lnfb = (const float*)d_in[22];
  float* out = (float*)d_out;

  const size_t NE = (size_t)BSROWS * EDIM;   // 4.19M floats
  float* h      = (float*)d_ws;
  float* region = h + NE;        // 4*NE floats: q,k,v,t1  (aliased by FFN mid)
  float* q    = region;
  float* kbuf = q + NE;
  float* vbuf = kbuf + NE;
  float* t1   = vbuf + NE;
  float* mid  = region;          // 4096*4096 == 4*NE exactly
  size_t base_bytes = (NE + 4 * NE) * sizeof(float);
  float* x = (ws_size >= base_bytes + NE * sizeof(float)) ? (t1 + NE) : out;

  hipMemcpyAsync(x, enc, NE * sizeof(float), hipMemcpyDeviceToDevice, stream);

  dim3 blk(256);
  dim3 gLN(BSROWS);
  dim3 gP(EDIM / BN, BSROWS / BM);   // (16, 32)
  dim3 gF1(FFD / BN, BSROWS / BM);   // (64, 32)
  dim3 gA(BNUM * HNUM * SLEN);       // 32768

  for (int l = 0; l < LNUM; ++l) {
    ln_kernel<<<gLN, blk, 0, stream>>>(x, ln1g + (size_t)l * EDIM, ln1b + (size_t)l * EDIM, h);
    gemm_f32<0><<<gP, blk, 0, stream>>>(h, Wq + (size_t)l * EDIM * EDIM, bq + (size_t)l * EDIM, nullptr, q, EDIM, EDIM);
    gemm_f32<0><<<gP, blk, 0, stream>>>(h, Wk + (size_t)l * EDIM * EDIM, bk + (size_t)l * EDIM, nullptr, kbuf, EDIM, EDIM);
    gemm_f32<0><<<gP, blk, 0, stream>>>(h, Wv + (size_t)l * EDIM * EDIM, bv + (size_t)l * EDIM, nullptr, vbuf, EDIM, EDIM);
    attn_kernel<<<gA, blk, 0, stream>>>(q, kbuf, vbuf, rel, lens,
                                        relk + (size_t)l * RNUM * DHD,
                                        relv + (size_t)l * RNUM * DHD, t1);
    gemm_f32<1><<<gP, blk, 0, stream>>>(t1, Wo + (size_t)l * EDIM * EDIM, bo + (size_t)l * EDIM, x, x, EDIM, EDIM);
    ln_kernel<<<gLN, blk, 0, stream>>>(x, ln2g + (size_t)l * EDIM, ln2b + (size_t)l * EDIM, h);
    gemm_f32<2><<<gF1, blk, 0, stream>>>(h, W1 + (size_t)l * EDIM * FFD, b1 + (size_t)l * FFD, nullptr, mid, FFD, EDIM);
    gemm_f32<1><<<gP, blk, 0, stream>>>(mid, W2 + (size_t)l * FFD * EDIM, b2 + (size_t)l * EDIM, x, x, EDIM, FFD);
  }
  ln_kernel<<<gLN, blk, 0, stream>>>(x, lnfg, lnfb, out);
}

// Round 4
// 4865.560 us; speedup vs baseline: 3.4362x; 3.4362x over previous
//
#include <hip/hip_runtime.h>

#define LNUM 6
#define EDIM 1024
#define HNUM 8
#define DHD  128
#define RNUM 33
#define FFD  4096
#define BNUM 8
#define SLEN 512
#define TOK  (BNUM*SLEN)   // 4096

typedef __attribute__((ext_vector_type(8))) short bf16x8;
typedef __attribute__((ext_vector_type(4))) float f32x4;
typedef unsigned short u16;
typedef unsigned int u32;

__device__ __forceinline__ u16 f2b(float f) {
  u32 u = __builtin_bit_cast(u32, f);
  u32 r = u + 0x7FFFu + ((u >> 16) & 1u);
  return (u16)(r >> 16);
}
__device__ __forceinline__ float blo(u32 p) { return __builtin_bit_cast(float, p << 16); }
__device__ __forceinline__ float bhi(u32 p) { return __builtin_bit_cast(float, p & 0xFFFF0000u); }
__device__ __forceinline__ u32 pck(float a, float b) { return (u32)f2b(a) | ((u32)f2b(b) << 16); }

// ---------------- LayerNorm ----------------
template<int BF16OUT>
__global__ __launch_bounds__(256) void ln_kernel(const float* __restrict__ x,
                                                 const float* __restrict__ g,
                                                 const float* __restrict__ be,
                                                 void* __restrict__ o) {
  int row = blockIdx.x;
  int t = threadIdx.x;
  const float* xr = x + (size_t)row * EDIM;
  float4 xv = *reinterpret_cast<const float4*>(xr + t * 4);
  float s1 = xv.x + xv.y + xv.z + xv.w;
  float s2 = xv.x*xv.x + xv.y*xv.y + xv.z*xv.z + xv.w*xv.w;
#pragma unroll
  for (int off = 32; off >= 1; off >>= 1) {
    s1 += __shfl_down(s1, off, 64);
    s2 += __shfl_down(s2, off, 64);
  }
  __shared__ float r1[4], r2[4];
  if ((t & 63) == 0) { r1[t >> 6] = s1; r2[t >> 6] = s2; }
  __syncthreads();
  s1 = r1[0] + r1[1] + r1[2] + r1[3];
  s2 = r2[0] + r2[1] + r2[2] + r2[3];
  float mean = s1 * (1.0f / EDIM);
  float var  = s2 * (1.0f / EDIM) - mean * mean;
  float rstd = rsqrtf(var + 1e-5f);
  float4 gv = *reinterpret_cast<const float4*>(g + t * 4);
  float4 bv = *reinterpret_cast<const float4*>(be + t * 4);
  float o0 = (xv.x - mean) * rstd * gv.x + bv.x;
  float o1 = (xv.y - mean) * rstd * gv.y + bv.y;
  float o2 = (xv.z - mean) * rstd * gv.z + bv.z;
  float o3 = (xv.w - mean) * rstd * gv.w + bv.w;
  if (BF16OUT) {
    ushort4 ov; ov.x = f2b(o0); ov.y = f2b(o1); ov.z = f2b(o2); ov.w = f2b(o3);
    *reinterpret_cast<ushort4*>((u16*)o + (size_t)row * EDIM + t * 4) = ov;
  } else {
    *reinterpret_cast<float4*>((float*)o + (size_t)row * EDIM + t * 4) = make_float4(o0, o1, o2, o3);
  }
}

// ---------------- Weight transpose: f32 [Kd][Nd] -> bf16 [Nd][Kd] ----------------
__global__ __launch_bounds__(256) void wtrans(const float* __restrict__ src0,
                                              u16* __restrict__ dst0,
                                              int Kd, int Nd, size_t sstride, size_t dstride) {
  __shared__ float Ts[32][33];
  const float* src = src0 + blockIdx.z * sstride;
  u16* dst = dst0 + blockIdx.z * dstride;
  int r0 = blockIdx.y * 32, c0 = blockIdx.x * 32;
  int ty = threadIdx.x >> 3, tx = threadIdx.x & 7;
  float4 v = *reinterpret_cast<const float4*>(src + (size_t)(r0 + ty) * Nd + c0 + tx * 4);
  Ts[ty][tx*4+0] = v.x; Ts[ty][tx*4+1] = v.y; Ts[ty][tx*4+2] = v.z; Ts[ty][tx*4+3] = v.w;
  __syncthreads();
  ushort4 o;
  o.x = f2b(Ts[tx*4+0][ty]); o.y = f2b(Ts[tx*4+1][ty]);
  o.z = f2b(Ts[tx*4+2][ty]); o.w = f2b(Ts[tx*4+3][ty]);
  *reinterpret_cast<ushort4*>(dst + (size_t)(c0 + ty) * Kd + r0 + tx * 4) = o;
}

// ---------------- bf16 MFMA GEMM: C[M,N] = A[M,K] @ B[N,K]^T ----------------
// BIASMODE: 0 = bias0[n], 1 = bias0[m], 2 = split (n<1024 ? bias0[n] : bias1[n-1024])
template<int BIASMODE, int ACT, int RES, int OUTBF16>
__global__ __launch_bounds__(256) void gemm_bt(const u16* __restrict__ A,
                                               const u16* __restrict__ B,
                                               const float* __restrict__ bias0,
                                               const float* __restrict__ bias1,
                                               const float* __restrict__ res,
                                               void* __restrict__ Cv,
                                               int M, int N, int K) {
  __shared__ u16 As[128 * 64];
  __shared__ u16 Bs[128 * 64];
  int t = threadIdx.x;
  int l = t & 63, w = t >> 6;
  int wm = w & 1, wn = w >> 1;
  int m0 = blockIdx.y * 128, n0 = blockIdx.x * 128;
  f32x4 acc[4][4] = {};
  int srow = t >> 1, scc = t & 1;
  const u16* Ap = A + (size_t)(m0 + srow) * K + scc * 32;
  const u16* Bp = B + (size_t)(n0 + srow) * K + scc * 32;
  uint4 av[4], bv[4];
#pragma unroll
  for (int u = 0; u < 4; ++u) {
    av[u] = *reinterpret_cast<const uint4*>(Ap + u * 8);
    bv[u] = *reinterpret_cast<const uint4*>(Bp + u * 8);
  }
  for (int k0 = 0; k0 < K; k0 += 64) {
    __syncthreads();   // previous iteration's LDS reads done
#pragma unroll
    for (int u = 0; u < 4; ++u) {
      int c = scc * 4 + u;
      *reinterpret_cast<uint4*>((char*)As + srow * 128 + ((c ^ (srow & 7)) * 16)) = av[u];
      *reinterpret_cast<uint4*>((char*)Bs + srow * 128 + ((c ^ (srow & 7)) * 16)) = bv[u];
    }
    __syncthreads();
    int kn = (k0 + 64 < K) ? (k0 + 64) : k0;
#pragma unroll
    for (int u = 0; u < 4; ++u) {
      av[u] = *reinterpret_cast<const uint4*>(Ap + kn + u * 8);
      bv[u] = *reinterpret_cast<const uint4*>(Bp + kn + u * 8);
    }
#pragma unroll
    for (int d4 = 0; d4 < 2; ++d4) {
      bf16x8 af[4];
#pragma unroll
      for (int fm = 0; fm < 4; ++fm) {
        int row = wm * 64 + fm * 16 + (l & 15);
        int c16 = d4 * 4 + (l >> 4);
        af[fm] = *reinterpret_cast<const bf16x8*>((char*)As + row * 128 + ((c16 ^ (row & 7)) * 16));
      }
#pragma unroll
      for (int fn = 0; fn < 4; ++fn) {
        int row = wn * 64 + fn * 16 + (l & 15);
        int c16 = d4 * 4 + (l >> 4);
        bf16x8 bf = *reinterpret_cast<const bf16x8*>((char*)Bs + row * 128 + ((c16 ^ (row & 7)) * 16));
#pragma unroll
        for (int fm = 0; fm < 4; ++fm)
          acc[fm][fn] = __builtin_amdgcn_mfma_f32_16x16x32_bf16(af[fm], bf, acc[fm][fn], 0, 0, 0);
      }
    }
  }
  // epilogue
#pragma unroll
  for (int fm = 0; fm < 4; ++fm)
#pragma unroll
    for (int fn = 0; fn < 4; ++fn)
#pragma unroll
      for (int e = 0; e < 4; ++e) {
        int m = m0 + wm * 64 + fm * 16 + (l >> 4) * 4 + e;
        int n = n0 + wn * 64 + fn * 16 + (l & 15);
        float v = acc[fm][fn][e];
        if (BIASMODE == 0) v += bias0[n];
        if (BIASMODE == 1) v += bias0[m];
        if (BIASMODE == 2) v += (n < 1024) ? bias0[n] : bias1[n - 1024];
        if (ACT == 1) v = fmaxf(v, 0.f);
        if (RES == 1) v += res[(size_t)m * N + n];
        if (OUTBF16) ((u16*)Cv)[(size_t)m * N + n] = f2b(v);
        else ((float*)Cv)[(size_t)m * N + n] = v;
      }
}

// ---------------- Relational attention (MFMA, block = (b,h,64-q-tile)) ----------------
#define SM_QS   0         // 64x128 bf16 swizzled  (16384)
#define SM_QR   16384     // qr f32 [64][48]       (12288)  -> overlaid by arelB bf16 [64][64]
#define SM_AREL 28672     // f32 [64][36]          (9216)
#define SM_SS   37888     // S/P bf16 [64][512] swz (65536) -> overlaid by Ot bf16 [64][128]
#define SM_KS   103424    // K/V/relvT tiles       (32768)
#define SM_LF   136192    // l[64] f32             (256)
#define SMEM_BYTES 136448

__global__ __launch_bounds__(256) void attn_kernel(const u16* __restrict__ qk,
                                                   const u16* __restrict__ vt,
                                                   const int* __restrict__ rel,
                                                   const int* __restrict__ lens,
                                                   const float* __restrict__ relk,
                                                   const float* __restrict__ relv,
                                                   u16* __restrict__ outb) {
  __align__(16) __shared__ char sm[SMEM_BYTES];
  u16* QS = (u16*)(sm + SM_QS);
  float* QR = (float*)(sm + SM_QR);
  float* AREL = (float*)(sm + SM_AREL);
  u16* SS = (u16*)(sm + SM_SS);
  u16* KS = (u16*)(sm + SM_KS);
  float* LF = (float*)(sm + SM_LF);

  int t = threadIdx.x;
  int l = t & 63, w = t >> 6;
  int bx = blockIdx.x;
  int it = bx & 7, hh = (bx >> 3) & 7, b = bx >> 6;
  int i0 = it * 64;
  int len = lens[b];
  const float scale = 0.08838834764831845f;

  // --- Phase A: stage Q tile (swizzled), zero arel ---
  {
    int i = t >> 2, sub = t & 3;
    const u16* src = qk + ((size_t)(b * SLEN + i0 + i)) * 2048 + hh * DHD;
#pragma unroll
    for (int u = 0; u < 4; ++u) {
      int c = sub * 4 + u;
      uint4 x = *reinterpret_cast<const uint4*>(src + c * 8);
      *reinterpret_cast<uint4*>((char*)QS + i * 256 + ((c * 16) ^ ((i & 7) << 4))) = x;
    }
    for (int idx = t; idx < 64 * 36; idx += 256) AREL[idx] = 0.f;
  }
  // --- Phase B: stage rel_k as bf16 [48][128] (rows>=33 zero), swizzled, into KS ---
  if (t < 192) {
    int r = t >> 2, sub = t & 3;
#pragma unroll
    for (int u = 0; u < 4; ++u) {
      int seg = sub * 4 + u;
      uint4 o;
      if (r < RNUM) {
        float4 f0 = *reinterpret_cast<const float4*>(relk + r * DHD + seg * 8);
        float4 f1 = *reinterpret_cast<const float4*>(relk + r * DHD + seg * 8 + 4);
        o.x = pck(f0.x, f0.y); o.y = pck(f0.z, f0.w);
        o.z = pck(f1.x, f1.y); o.w = pck(f1.z, f1.w);
      } else { o.x = o.y = o.z = o.w = 0u; }
      *reinterpret_cast<uint4*>((char*)KS + r * 256 + ((seg * 16) ^ ((r & 7) << 4))) = o;
    }
  }
  __syncthreads();
  // --- Phase B2: qr = Q @ rel_k^T  (wave w -> i-rows w*16..) ---
  {
    bf16x8 aq[4];
#pragma unroll
    for (int d4 = 0; d4 < 4; ++d4) {
      int row = w * 16 + (l & 15);
      aq[d4] = *reinterpret_cast<const bf16x8*>((char*)QS + row * 256 + (((d4 * 4 + (l >> 4)) * 16) ^ ((row & 7) << 4)));
    }
#pragma unroll
    for (int rb = 0; rb < 3; ++rb) {
      f32x4 acc = {};
#pragma unroll
      for (int d4 = 0; d4 < 4; ++d4) {
        int rr = rb * 16 + (l & 15);
        bf16x8 br = *reinterpret_cast<const bf16x8*>((char*)KS + rr * 256 + (((d4 * 4 + (l >> 4)) * 16) ^ ((rr & 7) << 4)));
        acc = __builtin_amdgcn_mfma_f32_16x16x32_bf16(aq[d4], br, acc, 0, 0, 0);
      }
#pragma unroll
      for (int e = 0; e < 4; ++e) {
        int i = w * 16 + (l >> 4) * 4 + e;
        QR[i * 48 + rb * 16 + (l & 15)] = acc[e];
      }
    }
  }
  // --- Phase C: S = Q@K^T + qr[rel] (4 key-tiles of 128) ---
  int ih = w & 1, jh = w >> 1;
  bf16x8 aq2[2][4];
  {
#pragma unroll
    for (int fi = 0; fi < 2; ++fi)
#pragma unroll
      for (int d4 = 0; d4 < 4; ++d4) {
        int row = ih * 32 + fi * 16 + (l & 15);
        aq2[fi][d4] = *reinterpret_cast<const bf16x8*>((char*)QS + row * 256 + (((d4 * 4 + (l >> 4)) * 16) ^ ((row & 7) << 4)));
      }
  }
  for (int kt = 0; kt < 4; ++kt) {
    __syncthreads();
    {
      int j = t >> 1, half = t & 1;
      const u16* src = qk + ((size_t)(b * SLEN + kt * 128 + j)) * 2048 + 1024 + hh * DHD;
#pragma unroll
      for (int u = 0; u < 8; ++u) {
        int c = half * 8 + u;
        uint4 x = *reinterpret_cast<const uint4*>(src + c * 8);
        *reinterpret_cast<uint4*>((char*)KS + j * 256 + ((c * 16) ^ ((j & 7) << 4))) = x;
      }
    }
    __syncthreads();
    f32x4 sacc[2][4] = {};
#pragma unroll
    for (int fj = 0; fj < 4; ++fj) {
      bf16x8 bk_[4];
#pragma unroll
      for (int d4 = 0; d4 < 4; ++d4) {
        int row = jh * 64 + fj * 16 + (l & 15);
        bk_[d4] = *reinterpret_cast<const bf16x8*>((char*)KS + row * 256 + (((d4 * 4 + (l >> 4)) * 16) ^ ((row & 7) << 4)));
      }
#pragma unroll
      for (int fi = 0; fi < 2; ++fi)
#pragma unroll
        for (int d4 = 0; d4 < 4; ++d4)
          sacc[fi][fj] = __builtin_amdgcn_mfma_f32_16x16x32_bf16(aq2[fi][d4], bk_[d4], sacc[fi][fj], 0, 0, 0);
    }
#pragma unroll
    for (int fi = 0; fi < 2; ++fi)
#pragma unroll
      for (int fj = 0; fj < 4; ++fj)
#pragma unroll
        for (int e = 0; e < 4; ++e) {
          int il = ih * 32 + fi * 16 + (l >> 4) * 4 + e;
          int jl = kt * 128 + jh * 64 + fj * 16 + (l & 15);
          int r = rel[((size_t)(b * SLEN + i0 + il)) * SLEN + jl];
          float s = (sacc[fi][fj][e] + QR[il * 48 + r]) * scale;
          if (i0 + il >= len || jl >= len) s = -1e9f;
          *reinterpret_cast<u16*>((char*)SS + il * 1024 + ((jl * 2) ^ ((il & 7) << 4))) = f2b(s);
        }
  }
  __syncthreads();
  // --- Phase D: softmax (thread -> row i = t>>2, quarter q4 = t&3 -> 128 keys) ---
  float lsum;
  {
    int i = t >> 2, q4 = t & 3;
    char* rb = (char*)SS + i * 1024;
    int swz = (i & 7) << 4;
    float mx = -3e38f;
#pragma unroll
    for (int c = 0; c < 16; ++c) {
      uint4 x = *reinterpret_cast<const uint4*>(rb + ((q4 * 256 + c * 16) ^ swz));
      mx = fmaxf(mx, fmaxf(fmaxf(blo(x.x), bhi(x.x)), fmaxf(blo(x.y), bhi(x.y))));
      mx = fmaxf(mx, fmaxf(fmaxf(blo(x.z), bhi(x.z)), fmaxf(blo(x.w), bhi(x.w))));
    }
    mx = fmaxf(mx, __shfl_xor(mx, 1, 64));
    mx = fmaxf(mx, __shfl_xor(mx, 2, 64));
    const int* relrow = rel + ((size_t)(b * SLEN + i0 + i)) * SLEN + q4 * 128;
    float sum = 0.f;
#pragma unroll
    for (int c = 0; c < 16; ++c) {
      char* addr = rb + ((q4 * 256 + c * 16) ^ swz);
      uint4 x = *reinterpret_cast<const uint4*>(addr);
      float p0 = __expf(blo(x.x) - mx), p1 = __expf(bhi(x.x) - mx);
      float p2 = __expf(blo(x.y) - mx), p3 = __expf(bhi(x.y) - mx);
      float p4 = __expf(blo(x.z) - mx), p5 = __expf(bhi(x.z) - mx);
      float p6 = __expf(blo(x.w) - mx), p7 = __expf(bhi(x.w) - mx);
      sum += ((p0 + p1) + (p2 + p3)) + ((p4 + p5) + (p6 + p7));
      uint4 y; y.x = pck(p0, p1); y.y = pck(p2, p3); y.z = pck(p4, p5); y.w = pck(p6, p7);
      *reinterpret_cast<uint4*>(addr) = y;
      int4 r0 = *reinterpret_cast<const int4*>(relrow + c * 8);
      int4 r1 = *reinterpret_cast<const int4*>(relrow + c * 8 + 4);
      atomicAdd(&AREL[i * 36 + r0.x], p0); atomicAdd(&AREL[i * 36 + r0.y], p1);
      atomicAdd(&AREL[i * 36 + r0.z], p2); atomicAdd(&AREL[i * 36 + r0.w], p3);
      atomicAdd(&AREL[i * 36 + r1.x], p4); atomicAdd(&AREL[i * 36 + r1.y], p5);
      atomicAdd(&AREL[i * 36 + r1.z], p6); atomicAdd(&AREL[i * 36 + r1.w], p7);
    }
    sum += __shfl_xor(sum, 1, 64);
    sum += __shfl_xor(sum, 2, 64);
    if (q4 == 0) LF[i] = sum;
    lsum = sum;
  }
  __syncthreads();
  // --- Phase D2: normalize P by 1/l; zero relvT region; build arelB = arel/l (bf16 [64][64]) ---
  {
    int i = t >> 2, q4 = t & 3;
    float inv = 1.0f / lsum;
    char* rb = (char*)SS + i * 1024;
    int swz = (i & 7) << 4;
#pragma unroll
    for (int c = 0; c < 16; ++c) {
      char* addr = rb + ((q4 * 256 + c * 16) ^ swz);
      uint4 x = *reinterpret_cast<const uint4*>(addr);
      uint4 y;
      y.x = pck(blo(x.x) * inv, bhi(x.x) * inv);
      y.y = pck(blo(x.y) * inv, bhi(x.y) * inv);
      y.z = pck(blo(x.z) * inv, bhi(x.z) * inv);
      y.w = pck(blo(x.w) * inv, bhi(x.w) * inv);
      *reinterpret_cast<uint4*>(addr) = y;
    }
    uint4 z; z.x = z.y = z.z = z.w = 0u;
    for (int idx = t; idx < 1024; idx += 256)
      *reinterpret_cast<uint4*>((char*)KS + idx * 16) = z;
    u16* ARB = (u16*)(sm + SM_QR);
    for (int idx = t; idx < 4096; idx += 256) {
      int ii = idx >> 6, r = idx & 63;
      float v = (r < RNUM) ? AREL[ii * 36 + r] * (1.0f / LF[ii]) : 0.f;
      *reinterpret_cast<u16*>((char*)ARB + ii * 128 + ((r * 2) ^ ((ii & 7) << 4))) = f2b(v);
    }
  }
  __syncthreads();
  // --- Phase D3: scatter rel_v^T bf16 [128 d][64 r] swizzled into KS ---
  for (int idx = t; idx < RNUM * DHD; idx += 256) {
    int r = idx >> 7, d = idx & 127;
    *reinterpret_cast<u16*>((char*)KS + d * 128 + ((r * 2) ^ ((d & 7) << 4))) = f2b(relv[idx]);
  }
  __syncthreads();
  // --- Phase E: acc = (arel/l) @ relv^T  (wave: ih2 = i-half, dh = d-half) ---
  int ih2 = w & 1, dh = w >> 1;
  f32x4 oacc[2][4] = {};
  {
    u16* ARB = (u16*)(sm + SM_QR);
#pragma unroll
    for (int kc = 0; kc < 2; ++kc) {
      bf16x8 aa[2];
#pragma unroll
      for (int fi = 0; fi < 2; ++fi) {
        int row = ih2 * 32 + fi * 16 + (l & 15);
        aa[fi] = *reinterpret_cast<const bf16x8*>((char*)ARB + row * 128 + (((kc * 4 + (l >> 4)) * 16) ^ ((row & 7) << 4)));
      }
#pragma unroll
      for (int fd = 0; fd < 4; ++fd) {
        int rowd = dh * 64 + fd * 16 + (l & 15);
        bf16x8 bb = *reinterpret_cast<const bf16x8*>((char*)KS + rowd * 128 + (((kc * 4 + (l >> 4)) * 16) ^ ((rowd & 7) << 4)));
#pragma unroll
        for (int fi = 0; fi < 2; ++fi)
          oacc[fi][fd] = __builtin_amdgcn_mfma_f32_16x16x32_bf16(aa[fi], bb, oacc[fi][fd], 0, 0, 0);
      }
    }
  }
  // --- Phase F: PV (4 value-tiles of 128 keys; Vt rows are features) ---
  for (int kt = 0; kt < 4; ++kt) {
    __syncthreads();
    {
      int d = t >> 1, half = t & 1;
      const u16* src = vt + ((size_t)(hh * DHD + d)) * TOK + b * SLEN + kt * 128;
#pragma unroll
      for (int u = 0; u < 8; ++u) {
        int c = half * 8 + u;
        uint4 x = *reinterpret_cast<const uint4*>(src + c * 8);
        *reinterpret_cast<uint4*>((char*)KS + d * 256 + ((c * 16) ^ ((d & 7) << 4))) = x;
      }
    }
    __syncthreads();
#pragma unroll
    for (int kc = 0; kc < 4; ++kc) {
      bf16x8 pa[2];
#pragma unroll
      for (int fi = 0; fi < 2; ++fi) {
        int row = ih2 * 32 + fi * 16 + (l & 15);
        pa[fi] = *reinterpret_cast<const bf16x8*>((char*)SS + row * 1024 + (((kt * 16 + kc * 4 + (l >> 4)) * 16) ^ ((row & 7) << 4)));
      }
#pragma unroll
      for (int fd = 0; fd < 4; ++fd) {
        int rowd = dh * 64 + fd * 16 + (l & 15);
        bf16x8 vb = *reinterpret_cast<const bf16x8*>((char*)KS + rowd * 256 + (((kc * 4 + (l >> 4)) * 16) ^ ((rowd & 7) << 4)));
#pragma unroll
        for (int fi = 0; fi < 2; ++fi)
          oacc[fi][fd] = __builtin_amdgcn_mfma_f32_16x16x32_bf16(pa[fi], vb, oacc[fi][fd], 0, 0, 0);
      }
    }
  }
  __syncthreads();   // all P reads done before Ot overlays SS
  // --- Phase G: write Ot bf16 [64][128] into SS region, then coalesced global store ---
#pragma unroll
  for (int fi = 0; fi < 2; ++fi)
#pragma unroll
    for (int fd = 0; fd < 4; ++fd)
#pragma unroll
      for (int e = 0; e < 4; ++e) {
        int i = ih2 * 32 + fi * 16 + (l >> 4) * 4 + e;
        int d = dh * 64 + fd * 16 + (l & 15);
        SS[i * 128 + d] = f2b(oacc[fi][fd][e]);
      }
  __syncthreads();
  {
    // Each (i, q4) thread stores 32 u16 = 64 B, covering d = q4*32 .. q4*32+31.
    // (Round-2/3 bug: only 2 of 4 uint4 stores -> upper half of each d-segment
    //  never written -> half the attention output was poison.)
    int i = t >> 2, q4 = t & 3;
    u16* dst = outb + ((size_t)(b * SLEN + i0 + i)) * EDIM + hh * DHD + q4 * 32;
    const char* srcb = (char*)SS + i * 256 + q4 * 64;
    uint4 x0 = *reinterpret_cast<const uint4*>(srcb);
    uint4 x1 = *reinterpret_cast<const uint4*>(srcb + 16);
    uint4 x2 = *reinterpret_cast<const uint4*>(srcb + 32);
    uint4 x3 = *reinterpret_cast<const uint4*>(srcb + 48);
    *reinterpret_cast<uint4*>(dst)      = x0;
    *reinterpret_cast<uint4*>(dst + 8)  = x1;
    *reinterpret_cast<uint4*>(dst + 16) = x2;
    *reinterpret_cast<uint4*>(dst + 24) = x3;
  }
}

// ---------------- host ----------------
extern "C" void kernel_launch(void* const* d_in, const int* in_sizes, int n_in,
                              void* d_out, int out_size, void* d_ws, size_t ws_size,
                              hipStream_t stream) {
  const float* enc  = (const float*)d_in[0];
  const int*   rel  = (const int*)d_in[1];
  const int*   lens = (const int*)d_in[2];
  const float* Wq = (const float*)d_in[3];
  const float* bq = (const float*)d_in[4];
  const float* Wk = (const float*)d_in[5];
  const float* bk = (const float*)d_in[6];
  const float* Wv = (const float*)d_in[7];
  const float* bv = (const float*)d_in[8];
  const float* Wo = (const float*)d_in[9];
  const float* bo = (const float*)d_in[10];
  const float* relk = (const float*)d_in[11];
  const float* relv = (const float*)d_in[12];
  const float* W1 = (const float*)d_in[13];
  const float* b1 = (const float*)d_in[14];
  const float* W2 = (const float*)d_in[15];
  const float* b2 = (const float*)d_in[16];
  const float* ln1g = (const float*)d_in[17];
  const float* ln1b = (const float*)d_in[18];
  const float* ln2g = (const float*)d_in[19];
  const float* ln2b = (const float*)d_in[20];
  const float* lnfg = (const float*)d_in[21];
  const float* lnfb = (const float*)d_in[22];
  float* out = (float*)d_out;

  char* W = (char*)d_ws;
  u16* h     = (u16*)W;                                // 8 MB
  char* U    = W + 8388608;
  u16* qkb   = (u16*)U;                                // 16 MB  [4096][2048]
  u16* vtb   = (u16*)(U + 16777216);                   // 8 MB   [1024][4096]
  u16* attno = (u16*)(U + 25165824);                   // 8 MB   [4096][1024]
  u16* mid   = (u16*)U;                                // 32 MB  [4096][4096] (aliases qkb/vtb/attno)
  bool xin = ws_size >= (size_t)83886080;
  float* x = xin ? (float*)(W + 41943040) : out;
  char* WT = W + (xin ? 58720256 : 41943040);
  bool big = ws_size >= (size_t)209715200;

  const size_t EE = (size_t)EDIM * EDIM;      // 1M
  const size_t EF = (size_t)EDIM * FFD;       // 4M

  u16 *WqkT, *WvT, *WoT, *W1T, *W2T;
  dim3 blk(256);
  if (big) {
    u16* wqk_all = (u16*)WT;                          // 6 * 2M elems
    u16* wv_all  = wqk_all + 6 * 2 * EE;
    u16* wo_all  = wv_all + 6 * EE;
    u16* w1_all  = wo_all + 6 * EE;
    u16* w2_all  = w1_all + 6 * EF;
    wtrans<<<dim3(32, 32, 6), blk, 0, stream>>>(Wq, wqk_all, 1024, 1024, EE, 2 * EE);
    wtrans<<<dim3(32, 32, 6), blk, 0, stream>>>(Wk, wqk_all + EE, 1024, 1024, EE, 2 * EE);
    wtrans<<<dim3(32, 32, 6), blk, 0, stream>>>(Wv, wv_all, 1024, 1024, EE, EE);
    wtrans<<<dim3(32, 32, 6), blk, 0, stream>>>(Wo, wo_all, 1024, 1024, EE, EE);
    wtrans<<<dim3(128, 32, 6), blk, 0, stream>>>(W1, w1_all, 1024, 4096, EF, EF);
    wtrans<<<dim3(32, 128, 6), blk, 0, stream>>>(W2, w2_all, 4096, 1024, EF, EF);
    WqkT = wqk_all; WvT = wv_all; WoT = wo_all; W1T = w1_all; W2T = w2_all;
  } else {
    WqkT = (u16*)WT;                 // 2M elems
    WvT  = WqkT + 2 * EE;            // 1M
    WoT  = WvT + EE;                 // 1M
    W1T  = WoT + EE;                 // 4M
    W2T  = W1T + EF;                 // 4M
  }

  dim3 gLN(TOK);
  for (int ll = 0; ll < LNUM; ++ll) {
    u16 *wqkT, *wvT, *woT, *w1T, *w2T;
    if (big) {
      wqkT = WqkT + (size_t)ll * 2 * EE; wvT = WvT + (size_t)ll * EE; woT = WoT + (size_t)ll * EE;
      w1T = W1T + (size_t)ll * EF; w2T = W2T + (size_t)ll * EF;
    } else {
      wqkT = WqkT; wvT = WvT; woT = WoT; w1T = W1T; w2T = W2T;
      wtrans<<<dim3(32, 32, 1), blk, 0, stream>>>(Wq + ll * EE, wqkT, 1024, 1024, 0, 0);
      wtrans<<<dim3(32, 32, 1), blk, 0, stream>>>(Wk + ll * EE, wqkT + EE, 1024, 1024, 0, 0);
      wtrans<<<dim3(32, 32, 1), blk, 0, stream>>>(Wv + ll * EE, wvT, 1024, 1024, 0, 0);
      wtrans<<<dim3(32, 32, 1), blk, 0, stream>>>(Wo + ll * EE, woT, 1024, 1024, 0, 0);
      wtrans<<<dim3(128, 32, 1), blk, 0, stream>>>(W1 + ll * EF, w1T, 1024, 4096, 0, 0);
      wtrans<<<dim3(32, 128, 1), blk, 0, stream>>>(W2 + ll * EF, w2T, 4096, 1024, 0, 0);
    }
    const float* xin_p = (ll == 0) ? enc : x;
    ln_kernel<1><<<gLN, blk, 0, stream>>>(xin_p, ln1g + ll * EDIM, ln1b + ll * EDIM, h);
    // QK projection: C = h @ [Wq|Wk]^T  -> qkb [4096][2048] bf16
    gemm_bt<2, 0, 0, 1><<<dim3(16, 32), blk, 0, stream>>>(h, wqkT, bq + ll * EDIM, bk + ll * EDIM,
                                                          nullptr, qkb, TOK, 2048, EDIM);
    // V transposed: Vt = Wv^T @ h^T -> vtb [1024][4096] bf16 (bias per row)
    gemm_bt<1, 0, 0, 1><<<dim3(32, 8), blk, 0, stream>>>(wvT, h, bv + ll * EDIM, nullptr,
                                                         nullptr, vtb, EDIM, TOK, EDIM);
    attn_kernel<<<dim3(512), blk, 0, stream>>>(qkb, vtb, rel, lens,
                                               relk + (size_t)ll * RNUM * DHD,
                                               relv + (size_t)ll * RNUM * DHD, attno);
    // O projection + residual -> x (f32)
    gemm_bt<0, 0, 1, 0><<<dim3(8, 32), blk, 0, stream>>>(attno, woT, bo + ll * EDIM, nullptr,
                                                         xin_p, x, TOK, EDIM, EDIM);
    ln_kernel<1><<<gLN, blk, 0, stream>>>(x, ln2g + ll * EDIM, ln2b + ll * EDIM, h);
    gemm_bt<0, 1, 0, 1><<<dim3(32, 32), blk, 0, stream>>>(h, w1T, b1 + ll * FFD, nullptr,
                                                          nullptr, mid, TOK, FFD, EDIM);
    gemm_bt<0, 0, 1, 0><<<dim3(8, 32), blk, 0, stream>>>(mid, w2T, b2 + ll * EDIM, nullptr,
                                                         x, x, TOK, EDIM, FFD);
  }
  ln_kernel<0><<<gLN, blk, 0, stream>>>(x, lnfg, lnfb, out);
}

// Round 5
// 2741.314 us; speedup vs baseline: 6.0989x; 1.7749x over previous
//
#include <hip/hip_runtime.h>

#define LNUM 6
#define EDIM 1024
#define HNUM 8
#define DHD  128
#define RNUM 33
#define FFD  4096
#define BNUM 8
#define SLEN 512
#define TOK  (BNUM*SLEN)   // 4096

typedef __attribute__((ext_vector_type(8))) short bf16x8;
typedef __attribute__((ext_vector_type(4))) float f32x4;
typedef unsigned short u16;
typedef unsigned int u32;

__device__ __forceinline__ u16 f2b(float f) {
  u32 u = __builtin_bit_cast(u32, f);
  u32 r = u + 0x7FFFu + ((u >> 16) & 1u);
  return (u16)(r >> 16);
}
__device__ __forceinline__ float blo(u32 p) { return __builtin_bit_cast(float, p << 16); }
__device__ __forceinline__ float bhi(u32 p) { return __builtin_bit_cast(float, p & 0xFFFF0000u); }
__device__ __forceinline__ u32 pck(float a, float b) { return (u32)f2b(a) | ((u32)f2b(b) << 16); }

// async global->LDS, 16B per lane. LDS dest is wave-uniform base + lane*16.
#define GL16(gp, lp) __builtin_amdgcn_global_load_lds(                        \
    (const __attribute__((address_space(1))) void*)(gp),                      \
    (__attribute__((address_space(3))) void*)(lp), 16, 0, 0)

// ---------------- LayerNorm ----------------
template<int BF16OUT>
__global__ __launch_bounds__(256) void ln_kernel(const float* __restrict__ x,
                                                 const float* __restrict__ g,
                                                 const float* __restrict__ be,
                                                 void* __restrict__ o) {
  int row = blockIdx.x;
  int t = threadIdx.x;
  const float* xr = x + (size_t)row * EDIM;
  float4 xv = *reinterpret_cast<const float4*>(xr + t * 4);
  float s1 = xv.x + xv.y + xv.z + xv.w;
  float s2 = xv.x*xv.x + xv.y*xv.y + xv.z*xv.z + xv.w*xv.w;
#pragma unroll
  for (int off = 32; off >= 1; off >>= 1) {
    s1 += __shfl_down(s1, off, 64);
    s2 += __shfl_down(s2, off, 64);
  }
  __shared__ float r1[4], r2[4];
  if ((t & 63) == 0) { r1[t >> 6] = s1; r2[t >> 6] = s2; }
  __syncthreads();
  s1 = r1[0] + r1[1] + r1[2] + r1[3];
  s2 = r2[0] + r2[1] + r2[2] + r2[3];
  float mean = s1 * (1.0f / EDIM);
  float var  = s2 * (1.0f / EDIM) - mean * mean;
  float rstd = rsqrtf(var + 1e-5f);
  float4 gv = *reinterpret_cast<const float4*>(g + t * 4);
  float4 bv = *reinterpret_cast<const float4*>(be + t * 4);
  float o0 = (xv.x - mean) * rstd * gv.x + bv.x;
  float o1 = (xv.y - mean) * rstd * gv.y + bv.y;
  float o2 = (xv.z - mean) * rstd * gv.z + bv.z;
  float o3 = (xv.w - mean) * rstd * gv.w + bv.w;
  if (BF16OUT) {
    ushort4 ov; ov.x = f2b(o0); ov.y = f2b(o1); ov.z = f2b(o2); ov.w = f2b(o3);
    *reinterpret_cast<ushort4*>((u16*)o + (size_t)row * EDIM + t * 4) = ov;
  } else {
    *reinterpret_cast<float4*>((float*)o + (size_t)row * EDIM + t * 4) = make_float4(o0, o1, o2, o3);
  }
}

// ---------------- Weight transpose: f32 [Kd][Nd] -> bf16 [Nd][Kd] ----------------
__global__ __launch_bounds__(256) void wtrans(const float* __restrict__ src0,
                                              u16* __restrict__ dst0,
                                              int Kd, int Nd, size_t sstride, size_t dstride) {
  __shared__ float Ts[32][33];
  const float* src = src0 + blockIdx.z * sstride;
  u16* dst = dst0 + blockIdx.z * dstride;
  int r0 = blockIdx.y * 32, c0 = blockIdx.x * 32;
  int ty = threadIdx.x >> 3, tx = threadIdx.x & 7;
  float4 v = *reinterpret_cast<const float4*>(src + (size_t)(r0 + ty) * Nd + c0 + tx * 4);
  Ts[ty][tx*4+0] = v.x; Ts[ty][tx*4+1] = v.y; Ts[ty][tx*4+2] = v.z; Ts[ty][tx*4+3] = v.w;
  __syncthreads();
  ushort4 o;
  o.x = f2b(Ts[tx*4+0][ty]); o.y = f2b(Ts[tx*4+1][ty]);
  o.z = f2b(Ts[tx*4+2][ty]); o.w = f2b(Ts[tx*4+3][ty]);
  *reinterpret_cast<ushort4*>(dst + (size_t)(c0 + ty) * Kd + r0 + tx * 4) = o;
}

// ---------------- bf16 MFMA GEMM: C[M,N] = A[M,K] @ B[N,K]^T ----------------
// Staging: global_load_lds width-16, linear LDS [128][64] (m97 structure).
// BIASMODE: 0 = bias0[n], 1 = bias0[m], 2 = split (n<1024 ? bias0[n] : bias1[n-1024])
template<int BIASMODE, int ACT, int RES, int OUTBF16>
__global__ __launch_bounds__(256) void gemm_bt(const u16* __restrict__ A,
                                               const u16* __restrict__ B,
                                               const float* __restrict__ bias0,
                                               const float* __restrict__ bias1,
                                               const float* __restrict__ res,
                                               void* __restrict__ Cv,
                                               int M, int N, int K) {
  __shared__ u16 As[128 * 64];
  __shared__ u16 Bs[128 * 64];
  int t = threadIdx.x;
  int l = t & 63, w = t >> 6;
  int wm = w & 1, wn = w >> 1;
  int m0 = blockIdx.y * 128, n0 = blockIdx.x * 128;
  f32x4 acc[4][4] = {};
  // staging geometry: chunk = w*4+u covers LDS bytes [chunk*1024, chunk*1024+1024):
  // lane l -> row chunk*8 + l/8, col (l%8)*8 (16B). Global src matches row-major [128][K].
  const u16* Agp = A + (size_t)(m0 + w * 32 + (l >> 3)) * K + (l & 7) * 8;
  const u16* Bgp = B + (size_t)(n0 + w * 32 + (l >> 3)) * K + (l & 7) * 8;
  u16* Alp = As + w * 4 * 512;
  u16* Blp = Bs + w * 4 * 512;
  for (int k0 = 0; k0 < K; k0 += 64) {
    __syncthreads();   // previous iteration's LDS reads done
#pragma unroll
    for (int u = 0; u < 4; ++u) {
      GL16(Agp + (size_t)(u * 8) * K + k0, Alp + u * 512);
      GL16(Bgp + (size_t)(u * 8) * K + k0, Blp + u * 512);
    }
    __syncthreads();   // compiler drains vmcnt(0) before s_barrier -> tiles ready
#pragma unroll
    for (int d4 = 0; d4 < 2; ++d4) {
      bf16x8 af[4];
#pragma unroll
      for (int fm = 0; fm < 4; ++fm) {
        int row = wm * 64 + fm * 16 + (l & 15);
        af[fm] = *reinterpret_cast<const bf16x8*>(As + row * 64 + (d4 * 4 + (l >> 4)) * 8);
      }
#pragma unroll
      for (int fn = 0; fn < 4; ++fn) {
        int row = wn * 64 + fn * 16 + (l & 15);
        bf16x8 bf = *reinterpret_cast<const bf16x8*>(Bs + row * 64 + (d4 * 4 + (l >> 4)) * 8);
#pragma unroll
        for (int fm = 0; fm < 4; ++fm)
          acc[fm][fn] = __builtin_amdgcn_mfma_f32_16x16x32_bf16(af[fm], bf, acc[fm][fn], 0, 0, 0);
      }
    }
  }
  // epilogue
#pragma unroll
  for (int fm = 0; fm < 4; ++fm)
#pragma unroll
    for (int fn = 0; fn < 4; ++fn)
#pragma unroll
      for (int e = 0; e < 4; ++e) {
        int m = m0 + wm * 64 + fm * 16 + (l >> 4) * 4 + e;
        int n = n0 + wn * 64 + fn * 16 + (l & 15);
        float v = acc[fm][fn][e];
        if (BIASMODE == 0) v += bias0[n];
        if (BIASMODE == 1) v += bias0[m];
        if (BIASMODE == 2) v += (n < 1024) ? bias0[n] : bias1[n - 1024];
        if (ACT == 1) v = fmaxf(v, 0.f);
        if (RES == 1) v += res[(size_t)m * N + n];
        if (OUTBF16) ((u16*)Cv)[(size_t)m * N + n] = f2b(v);
        else ((float*)Cv)[(size_t)m * N + n] = v;
      }
}

// ---------------- Relational attention (MFMA, block = (b,h,64-q-tile)) ----------------
#define SM_QS   0         // 64x128 bf16 swizzled  (16384)
#define SM_QR   16384     // qr f32 [64][48]       (12288)  -> overlaid by arelB bf16 [64][64]
#define SM_AREL 28672     // f32 [64][36]          (9216)
#define SM_SS   37888     // S/P bf16 [64][512] swz (65536) -> overlaid by Ot bf16 [64][128]
#define SM_KS   103424    // K/V/relvT tiles       (32768)
#define SM_LF   136192    // l[64] f32             (256)
#define SMEM_BYTES 136448

__global__ __launch_bounds__(256) void attn_kernel(const u16* __restrict__ qk,
                                                   const u16* __restrict__ vt,
                                                   const int* __restrict__ rel,
                                                   const int* __restrict__ lens,
                                                   const float* __restrict__ relk,
                                                   const float* __restrict__ relv,
                                                   u16* __restrict__ outb) {
  __align__(16) __shared__ char sm[SMEM_BYTES];
  u16* QS = (u16*)(sm + SM_QS);
  float* QR = (float*)(sm + SM_QR);
  float* AREL = (float*)(sm + SM_AREL);
  u16* SS = (u16*)(sm + SM_SS);
  u16* KS = (u16*)(sm + SM_KS);
  float* LF = (float*)(sm + SM_LF);

  int t = threadIdx.x;
  int l = t & 63, w = t >> 6;
  int bx = blockIdx.x;
  int it = bx & 7, hh = (bx >> 3) & 7, b = bx >> 6;
  int i0 = it * 64;
  int len = lens[b];
  const float scale = 0.08838834764831845f;

  // --- Phase A: stage Q tile (swizzled), zero arel ---
  {
    int i = t >> 2, sub = t & 3;
    const u16* src = qk + ((size_t)(b * SLEN + i0 + i)) * 2048 + hh * DHD;
#pragma unroll
    for (int u = 0; u < 4; ++u) {
      int c = sub * 4 + u;
      uint4 x = *reinterpret_cast<const uint4*>(src + c * 8);
      *reinterpret_cast<uint4*>((char*)QS + i * 256 + ((c * 16) ^ ((i & 7) << 4))) = x;
    }
    for (int idx = t; idx < 64 * 36; idx += 256) AREL[idx] = 0.f;
  }
  // --- Phase B: stage rel_k as bf16 [48][128] (rows>=33 zero), swizzled, into KS ---
  if (t < 192) {
    int r = t >> 2, sub = t & 3;
#pragma unroll
    for (int u = 0; u < 4; ++u) {
      int seg = sub * 4 + u;
      uint4 o;
      if (r < RNUM) {
        float4 f0 = *reinterpret_cast<const float4*>(relk + r * DHD + seg * 8);
        float4 f1 = *reinterpret_cast<const float4*>(relk + r * DHD + seg * 8 + 4);
        o.x = pck(f0.x, f0.y); o.y = pck(f0.z, f0.w);
        o.z = pck(f1.x, f1.y); o.w = pck(f1.z, f1.w);
      } else { o.x = o.y = o.z = o.w = 0u; }
      *reinterpret_cast<uint4*>((char*)KS + r * 256 + ((seg * 16) ^ ((r & 7) << 4))) = o;
    }
  }
  __syncthreads();
  // --- Phase B2: qr = Q @ rel_k^T  (wave w -> i-rows w*16..) ---
  {
    bf16x8 aq[4];
#pragma unroll
    for (int d4 = 0; d4 < 4; ++d4) {
      int row = w * 16 + (l & 15);
      aq[d4] = *reinterpret_cast<const bf16x8*>((char*)QS + row * 256 + (((d4 * 4 + (l >> 4)) * 16) ^ ((row & 7) << 4)));
    }
#pragma unroll
    for (int rb = 0; rb < 3; ++rb) {
      f32x4 acc = {};
#pragma unroll
      for (int d4 = 0; d4 < 4; ++d4) {
        int rr = rb * 16 + (l & 15);
        bf16x8 br = *reinterpret_cast<const bf16x8*>((char*)KS + rr * 256 + (((d4 * 4 + (l >> 4)) * 16) ^ ((rr & 7) << 4)));
        acc = __builtin_amdgcn_mfma_f32_16x16x32_bf16(aq[d4], br, acc, 0, 0, 0);
      }
#pragma unroll
      for (int e = 0; e < 4; ++e) {
        int i = w * 16 + (l >> 4) * 4 + e;
        QR[i * 48 + rb * 16 + (l & 15)] = acc[e];
      }
    }
  }
  // --- Phase C: S = Q@K^T + qr[rel] (4 key-tiles of 128) ---
  int ih = w & 1, jh = w >> 1;
  bf16x8 aq2[2][4];
  {
#pragma unroll
    for (int fi = 0; fi < 2; ++fi)
#pragma unroll
      for (int d4 = 0; d4 < 4; ++d4) {
        int row = ih * 32 + fi * 16 + (l & 15);
        aq2[fi][d4] = *reinterpret_cast<const bf16x8*>((char*)QS + row * 256 + (((d4 * 4 + (l >> 4)) * 16) ^ ((row & 7) << 4)));
      }
  }
  for (int kt = 0; kt < 4; ++kt) {
    __syncthreads();
    {
      int j = t >> 1, half = t & 1;
      const u16* src = qk + ((size_t)(b * SLEN + kt * 128 + j)) * 2048 + 1024 + hh * DHD;
#pragma unroll
      for (int u = 0; u < 8; ++u) {
        int c = half * 8 + u;
        uint4 x = *reinterpret_cast<const uint4*>(src + c * 8);
        *reinterpret_cast<uint4*>((char*)KS + j * 256 + ((c * 16) ^ ((j & 7) << 4))) = x;
      }
    }
    __syncthreads();
    f32x4 sacc[2][4] = {};
#pragma unroll
    for (int fj = 0; fj < 4; ++fj) {
      bf16x8 bk_[4];
#pragma unroll
      for (int d4 = 0; d4 < 4; ++d4) {
        int row = jh * 64 + fj * 16 + (l & 15);
        bk_[d4] = *reinterpret_cast<const bf16x8*>((char*)KS + row * 256 + (((d4 * 4 + (l >> 4)) * 16) ^ ((row & 7) << 4)));
      }
#pragma unroll
      for (int fi = 0; fi < 2; ++fi)
#pragma unroll
        for (int d4 = 0; d4 < 4; ++d4)
          sacc[fi][fj] = __builtin_amdgcn_mfma_f32_16x16x32_bf16(aq2[fi][d4], bk_[d4], sacc[fi][fj], 0, 0, 0);
    }
#pragma unroll
    for (int fi = 0; fi < 2; ++fi)
#pragma unroll
      for (int fj = 0; fj < 4; ++fj)
#pragma unroll
        for (int e = 0; e < 4; ++e) {
          int il = ih * 32 + fi * 16 + (l >> 4) * 4 + e;
          int jl = kt * 128 + jh * 64 + fj * 16 + (l & 15);
          int r = rel[((size_t)(b * SLEN + i0 + il)) * SLEN + jl];
          float s = (sacc[fi][fj][e] + QR[il * 48 + r]) * scale;
          if (i0 + il >= len || jl >= len) s = -1e9f;
          *reinterpret_cast<u16*>((char*)SS + il * 1024 + ((jl * 2) ^ ((il & 7) << 4))) = f2b(s);
        }
  }
  __syncthreads();
  // --- Phase D: softmax (thread -> row i = t>>2, quarter q4 = t&3 -> 128 keys) ---
  float lsum;
  {
    int i = t >> 2, q4 = t & 3;
    char* rb = (char*)SS + i * 1024;
    int swz = (i & 7) << 4;
    float mx = -3e38f;
#pragma unroll
    for (int c = 0; c < 16; ++c) {
      uint4 x = *reinterpret_cast<const uint4*>(rb + ((q4 * 256 + c * 16) ^ swz));
      mx = fmaxf(mx, fmaxf(fmaxf(blo(x.x), bhi(x.x)), fmaxf(blo(x.y), bhi(x.y))));
      mx = fmaxf(mx, fmaxf(fmaxf(blo(x.z), bhi(x.z)), fmaxf(blo(x.w), bhi(x.w))));
    }
    mx = fmaxf(mx, __shfl_xor(mx, 1, 64));
    mx = fmaxf(mx, __shfl_xor(mx, 2, 64));
    const int* relrow = rel + ((size_t)(b * SLEN + i0 + i)) * SLEN + q4 * 128;
    float sum = 0.f;
#pragma unroll
    for (int c = 0; c < 16; ++c) {
      char* addr = rb + ((q4 * 256 + c * 16) ^ swz);
      uint4 x = *reinterpret_cast<const uint4*>(addr);
      float p0 = __expf(blo(x.x) - mx), p1 = __expf(bhi(x.x) - mx);
      float p2 = __expf(blo(x.y) - mx), p3 = __expf(bhi(x.y) - mx);
      float p4 = __expf(blo(x.z) - mx), p5 = __expf(bhi(x.z) - mx);
      float p6 = __expf(blo(x.w) - mx), p7 = __expf(bhi(x.w) - mx);
      sum += ((p0 + p1) + (p2 + p3)) + ((p4 + p5) + (p6 + p7));
      uint4 y; y.x = pck(p0, p1); y.y = pck(p2, p3); y.z = pck(p4, p5); y.w = pck(p6, p7);
      *reinterpret_cast<uint4*>(addr) = y;
      int4 r0 = *reinterpret_cast<const int4*>(relrow + c * 8);
      int4 r1 = *reinterpret_cast<const int4*>(relrow + c * 8 + 4);
      atomicAdd(&AREL[i * 36 + r0.x], p0); atomicAdd(&AREL[i * 36 + r0.y], p1);
      atomicAdd(&AREL[i * 36 + r0.z], p2); atomicAdd(&AREL[i * 36 + r0.w], p3);
      atomicAdd(&AREL[i * 36 + r1.x], p4); atomicAdd(&AREL[i * 36 + r1.y], p5);
      atomicAdd(&AREL[i * 36 + r1.z], p6); atomicAdd(&AREL[i * 36 + r1.w], p7);
    }
    sum += __shfl_xor(sum, 1, 64);
    sum += __shfl_xor(sum, 2, 64);
    if (q4 == 0) LF[i] = sum;
    lsum = sum;
  }
  __syncthreads();
  // --- Phase D2: normalize P by 1/l; zero relvT region; build arelB = arel/l (bf16 [64][64]) ---
  {
    int i = t >> 2, q4 = t & 3;
    float inv = 1.0f / lsum;
    char* rb = (char*)SS + i * 1024;
    int swz = (i & 7) << 4;
#pragma unroll
    for (int c = 0; c < 16; ++c) {
      char* addr = rb + ((q4 * 256 + c * 16) ^ swz);
      uint4 x = *reinterpret_cast<const uint4*>(addr);
      uint4 y;
      y.x = pck(blo(x.x) * inv, bhi(x.x) * inv);
      y.y = pck(blo(x.y) * inv, bhi(x.y) * inv);
      y.z = pck(blo(x.z) * inv, bhi(x.z) * inv);
      y.w = pck(blo(x.w) * inv, bhi(x.w) * inv);
      *reinterpret_cast<uint4*>(addr) = y;
    }
    uint4 z; z.x = z.y = z.z = z.w = 0u;
    for (int idx = t; idx < 1024; idx += 256)
      *reinterpret_cast<uint4*>((char*)KS + idx * 16) = z;
    u16* ARB = (u16*)(sm + SM_QR);
    for (int idx = t; idx < 4096; idx += 256) {
      int ii = idx >> 6, r = idx & 63;
      float v = (r < RNUM) ? AREL[ii * 36 + r] * (1.0f / LF[ii]) : 0.f;
      *reinterpret_cast<u16*>((char*)ARB + ii * 128 + ((r * 2) ^ ((ii & 7) << 4))) = f2b(v);
    }
  }
  __syncthreads();
  // --- Phase D3: scatter rel_v^T bf16 [128 d][64 r] swizzled into KS ---
  for (int idx = t; idx < RNUM * DHD; idx += 256) {
    int r = idx >> 7, d = idx & 127;
    *reinterpret_cast<u16*>((char*)KS + d * 128 + ((r * 2) ^ ((d & 7) << 4))) = f2b(relv[idx]);
  }
  __syncthreads();
  // --- Phase E: acc = (arel/l) @ relv^T  (wave: ih2 = i-half, dh = d-half) ---
  int ih2 = w & 1, dh = w >> 1;
  f32x4 oacc[2][4] = {};
  {
    u16* ARB = (u16*)(sm + SM_QR);
#pragma unroll
    for (int kc = 0; kc < 2; ++kc) {
      bf16x8 aa[2];
#pragma unroll
      for (int fi = 0; fi < 2; ++fi) {
        int row = ih2 * 32 + fi * 16 + (l & 15);
        aa[fi] = *reinterpret_cast<const bf16x8*>((char*)ARB + row * 128 + (((kc * 4 + (l >> 4)) * 16) ^ ((row & 7) << 4)));
      }
#pragma unroll
      for (int fd = 0; fd < 4; ++fd) {
        int rowd = dh * 64 + fd * 16 + (l & 15);
        bf16x8 bb = *reinterpret_cast<const bf16x8*>((char*)KS + rowd * 128 + (((kc * 4 + (l >> 4)) * 16) ^ ((rowd & 7) << 4)));
#pragma unroll
        for (int fi = 0; fi < 2; ++fi)
          oacc[fi][fd] = __builtin_amdgcn_mfma_f32_16x16x32_bf16(aa[fi], bb, oacc[fi][fd], 0, 0, 0);
      }
    }
  }
  // --- Phase F: PV (4 value-tiles of 128 keys; Vt rows are features) ---
  for (int kt = 0; kt < 4; ++kt) {
    __syncthreads();
    {
      int d = t >> 1, half = t & 1;
      const u16* src = vt + ((size_t)(hh * DHD + d)) * TOK + b * SLEN + kt * 128;
#pragma unroll
      for (int u = 0; u < 8; ++u) {
        int c = half * 8 + u;
        uint4 x = *reinterpret_cast<const uint4*>(src + c * 8);
        *reinterpret_cast<uint4*>((char*)KS + d * 256 + ((c * 16) ^ ((d & 7) << 4))) = x;
      }
    }
    __syncthreads();
#pragma unroll
    for (int kc = 0; kc < 4; ++kc) {
      bf16x8 pa[2];
#pragma unroll
      for (int fi = 0; fi < 2; ++fi) {
        int row = ih2 * 32 + fi * 16 + (l & 15);
        pa[fi] = *reinterpret_cast<const bf16x8*>((char*)SS + row * 1024 + (((kt * 16 + kc * 4 + (l >> 4)) * 16) ^ ((row & 7) << 4)));
      }
#pragma unroll
      for (int fd = 0; fd < 4; ++fd) {
        int rowd = dh * 64 + fd * 16 + (l & 15);
        bf16x8 vb = *reinterpret_cast<const bf16x8*>((char*)KS + rowd * 256 + (((kc * 4 + (l >> 4)) * 16) ^ ((rowd & 7) << 4)));
#pragma unroll
        for (int fi = 0; fi < 2; ++fi)
          oacc[fi][fd] = __builtin_amdgcn_mfma_f32_16x16x32_bf16(pa[fi], vb, oacc[fi][fd], 0, 0, 0);
      }
    }
  }
  __syncthreads();   // all P reads done before Ot overlays SS
  // --- Phase G: write Ot bf16 [64][128] into SS region, then coalesced global store ---
#pragma unroll
  for (int fi = 0; fi < 2; ++fi)
#pragma unroll
    for (int fd = 0; fd < 4; ++fd)
#pragma unroll
      for (int e = 0; e < 4; ++e) {
        int i = ih2 * 32 + fi * 16 + (l >> 4) * 4 + e;
        int d = dh * 64 + fd * 16 + (l & 15);
        SS[i * 128 + d] = f2b(oacc[fi][fd][e]);
      }
  __syncthreads();
  {
    int i = t >> 2, q4 = t & 3;
    u16* dst = outb + ((size_t)(b * SLEN + i0 + i)) * EDIM + hh * DHD + q4 * 32;
    const char* srcb = (char*)SS + i * 256 + q4 * 64;
    uint4 x0 = *reinterpret_cast<const uint4*>(srcb);
    uint4 x1 = *reinterpret_cast<const uint4*>(srcb + 16);
    uint4 x2 = *reinterpret_cast<const uint4*>(srcb + 32);
    uint4 x3 = *reinterpret_cast<const uint4*>(srcb + 48);
    *reinterpret_cast<uint4*>(dst)      = x0;
    *reinterpret_cast<uint4*>(dst + 8)  = x1;
    *reinterpret_cast<uint4*>(dst + 16) = x2;
    *reinterpret_cast<uint4*>(dst + 24) = x3;
  }
}

// ---------------- host ----------------
extern "C" void kernel_launch(void* const* d_in, const int* in_sizes, int n_in,
                              void* d_out, int out_size, void* d_ws, size_t ws_size,
                              hipStream_t stream) {
  const float* enc  = (const float*)d_in[0];
  const int*   rel  = (const int*)d_in[1];
  const int*   lens = (const int*)d_in[2];
  const float* Wq = (const float*)d_in[3];
  const float* bq = (const float*)d_in[4];
  const float* Wk = (const float*)d_in[5];
  const float* bk = (const float*)d_in[6];
  const float* Wv = (const float*)d_in[7];
  const float* bv = (const float*)d_in[8];
  const float* Wo = (const float*)d_in[9];
  const float* bo = (const float*)d_in[10];
  const float* relk = (const float*)d_in[11];
  const float* relv = (const float*)d_in[12];
  const float* W1 = (const float*)d_in[13];
  const float* b1 = (const float*)d_in[14];
  const float* W2 = (const float*)d_in[15];
  const float* b2 = (const float*)d_in[16];
  const float* ln1g = (const float*)d_in[17];
  const float* ln1b = (const float*)d_in[18];
  const float* ln2g = (const float*)d_in[19];
  const float* ln2b = (const float*)d_in[20];
  const float* lnfg = (const float*)d_in[21];
  const float* lnfb = (const float*)d_in[22];
  float* out = (float*)d_out;

  char* W = (char*)d_ws;
  u16* h     = (u16*)W;                                // 8 MB
  char* U    = W + 8388608;
  u16* qkb   = (u16*)U;                                // 16 MB  [4096][2048]
  u16* vtb   = (u16*)(U + 16777216);                   // 8 MB   [1024][4096]
  u16* attno = (u16*)(U + 25165824);                   // 8 MB   [4096][1024]
  u16* mid   = (u16*)U;                                // 32 MB  [4096][4096] (aliases qkb/vtb/attno)
  bool xin = ws_size >= (size_t)83886080;
  float* x = xin ? (float*)(W + 41943040) : out;
  char* WT = W + (xin ? 58720256 : 41943040);
  bool big = ws_size >= (size_t)209715200;

  const size_t EE = (size_t)EDIM * EDIM;      // 1M
  const size_t EF = (size_t)EDIM * FFD;       // 4M

  u16 *WqkT, *WvT, *WoT, *W1T, *W2T;
  dim3 blk(256);
  if (big) {
    u16* wqk_all = (u16*)WT;                          // 6 * 2M elems
    u16* wv_all  = wqk_all + 6 * 2 * EE;
    u16* wo_all  = wv_all + 6 * EE;
    u16* w1_all  = wo_all + 6 * EE;
    u16* w2_all  = w1_all + 6 * EF;
    wtrans<<<dim3(32, 32, 6), blk, 0, stream>>>(Wq, wqk_all, 1024, 1024, EE, 2 * EE);
    wtrans<<<dim3(32, 32, 6), blk, 0, stream>>>(Wk, wqk_all + EE, 1024, 1024, EE, 2 * EE);
    wtrans<<<dim3(32, 32, 6), blk, 0, stream>>>(Wv, wv_all, 1024, 1024, EE, EE);
    wtrans<<<dim3(32, 32, 6), blk, 0, stream>>>(Wo, wo_all, 1024, 1024, EE, EE);
    wtrans<<<dim3(128, 32, 6), blk, 0, stream>>>(W1, w1_all, 1024, 4096, EF, EF);
    wtrans<<<dim3(32, 128, 6), blk, 0, stream>>>(W2, w2_all, 4096, 1024, EF, EF);
    WqkT = wqk_all; WvT = wv_all; WoT = wo_all; W1T = w1_all; W2T = w2_all;
  } else {
    WqkT = (u16*)WT;                 // 2M elems
    WvT  = WqkT + 2 * EE;            // 1M
    WoT  = WvT + EE;                 // 1M
    W1T  = WoT + EE;                 // 4M
    W2T  = W1T + EF;                 // 4M
  }

  dim3 gLN(TOK);
  for (int ll = 0; ll < LNUM; ++ll) {
    u16 *wqkT, *wvT, *woT, *w1T, *w2T;
    if (big) {
      wqkT = WqkT + (size_t)ll * 2 * EE; wvT = WvT + (size_t)ll * EE; woT = WoT + (size_t)ll * EE;
      w1T = W1T + (size_t)ll * EF; w2T = W2T + (size_t)ll * EF;
    } else {
      wqkT = WqkT; wvT = WvT; woT = WoT; w1T = W1T; w2T = W2T;
      wtrans<<<dim3(32, 32, 1), blk, 0, stream>>>(Wq + ll * EE, wqkT, 1024, 1024, 0, 0);
      wtrans<<<dim3(32, 32, 1), blk, 0, stream>>>(Wk + ll * EE, wqkT + EE, 1024, 1024, 0, 0);
      wtrans<<<dim3(32, 32, 1), blk, 0, stream>>>(Wv + ll * EE, wvT, 1024, 1024, 0, 0);
      wtrans<<<dim3(32, 32, 1), blk, 0, stream>>>(Wo + ll * EE, woT, 1024, 1024, 0, 0);
      wtrans<<<dim3(128, 32, 1), blk, 0, stream>>>(W1 + ll * EF, w1T, 1024, 4096, 0, 0);
      wtrans<<<dim3(32, 128, 1), blk, 0, stream>>>(W2 + ll * EF, w2T, 4096, 1024, 0, 0);
    }
    const float* xin_p = (ll == 0) ? enc : x;
    ln_kernel<1><<<gLN, blk, 0, stream>>>(xin_p, ln1g + ll * EDIM, ln1b + ll * EDIM, h);
    // QK projection: C = h @ [Wq|Wk]^T  -> qkb [4096][2048] bf16
    gemm_bt<2, 0, 0, 1><<<dim3(16, 32), blk, 0, stream>>>(h, wqkT, bq + ll * EDIM, bk + ll * EDIM,
                                                          nullptr, qkb, TOK, 2048, EDIM);
    // V transposed: Vt = Wv^T @ h^T -> vtb [1024][4096] bf16 (bias per row)
    gemm_bt<1, 0, 0, 1><<<dim3(32, 8), blk, 0, stream>>>(wvT, h, bv + ll * EDIM, nullptr,
                                                         nullptr, vtb, EDIM, TOK, EDIM);
    attn_kernel<<<dim3(512), blk, 0, stream>>>(qkb, vtb, rel, lens,
                                               relk + (size_t)ll * RNUM * DHD,
                                               relv + (size_t)ll * RNUM * DHD, attno);
    // O projection + residual -> x (f32)
    gemm_bt<0, 0, 1, 0><<<dim3(8, 32), blk, 0, stream>>>(attno, woT, bo + ll * EDIM, nullptr,
                                                         xin_p, x, TOK, EDIM, EDIM);
    ln_kernel<1><<<gLN, blk, 0, stream>>>(x, ln2g + ll * EDIM, ln2b + ll * EDIM, h);
    gemm_bt<0, 1, 0, 1><<<dim3(32, 32), blk, 0, stream>>>(h, w1T, b1 + ll * FFD, nullptr,
                                                          nullptr, mid, TOK, FFD, EDIM);
    gemm_bt<0, 0, 1, 0><<<dim3(8, 32), blk, 0, stream>>>(mid, w2T, b2 + ll * EDIM, nullptr,
                                                         x, x, TOK, EDIM, FFD);
  }
  ln_kernel<0><<<gLN, blk, 0, stream>>>(x, lnfg, lnfb, out);
}